// Round 5
// baseline (121.148 us; speedup 1.0000x reference)
//
#include <hip/hip_runtime.h>
#include <math.h>

#define Bc 64
#define Nc 100
#define Fc 2048
#define Kc 16
#define NKc 8
#define BN (Bc*Nc)      // 6400
#define MO 1024
#define TWO_PI 6.283185307179586f

typedef __attribute__((ext_vector_type(8))) short bf16x8;
typedef __attribute__((ext_vector_type(4))) float f32x4;

__device__ __forceinline__ unsigned short f2bf(float x) {
    union { float f; unsigned u; } c; c.f = x;
    unsigned r = c.u + 0x7FFFu + ((c.u >> 16) & 1u);
    return (unsigned short)(r >> 16);
}
__device__ __forceinline__ float bf2f(unsigned short x) {
    return __uint_as_float((unsigned)x << 16);
}

// ---------------------------------------------------------------------------
// fused fp32 -> bf16 (RNE) for v and W (dst = [vb | Wb] contiguous)
// ---------------------------------------------------------------------------
__global__ __launch_bounds__(256) void cvt_both(
    const float* __restrict__ v, const float* __restrict__ W,
    unsigned short* __restrict__ dst, int n8v, int n8tot)
{
    for (int i = blockIdx.x * blockDim.x + threadIdx.x; i < n8tot;
         i += gridDim.x * blockDim.x) {
        const float* src = (i < n8v) ? (v + (size_t)i * 8)
                                     : (W + (size_t)(i - n8v) * 8);
        const float4 x0 = ((const float4*)src)[0];
        const float4 x1 = ((const float4*)src)[1];
        bf16x8 o;
        o[0]=(short)f2bf(x0.x); o[1]=(short)f2bf(x0.y);
        o[2]=(short)f2bf(x0.z); o[3]=(short)f2bf(x0.w);
        o[4]=(short)f2bf(x1.x); o[5]=(short)f2bf(x1.y);
        o[6]=(short)f2bf(x1.z); o[7]=(short)f2bf(x1.w);
        *(bf16x8*)(dst + (size_t)i * 8) = o;
    }
}

// ---------------------------------------------------------------------------
// bf16 MFMA GEMM -> bf16 P, 2-phase dbuf + T2 swizzle (round-4 proven):
//   P[i][n] = sum_f vb[i][f] * Wb[n][f]
// 128x64 tile, BK=64, 2 waves (wm = 0/1), wave tile 64x64, 800 blocks
// (balanced grid ~3 blocks/CU at 48 KB LDS). XCD-chunked block swizzle:
// the 16 N-blocks sharing an A-panel run on one XCD (A L2-hits).
// ---------------------------------------------------------------------------
#define GBM 128
#define GBN 64
#define GBK 64
#define NT (Fc/GBK)     // 32

#define SYNC() do { asm volatile("s_waitcnt vmcnt(0)" ::: "memory"); \
                    __builtin_amdgcn_s_barrier(); \
                    __builtin_amdgcn_sched_barrier(0); } while (0)

__global__ __launch_bounds__(128) void gemm_bf16_db(
    const unsigned short* __restrict__ A,
    const unsigned short* __restrict__ B,
    unsigned short* __restrict__ P)
{
    __shared__ __align__(16) unsigned short Al[2][GBM][GBK];  // 2 x 16 KB
    __shared__ __align__(16) unsigned short Bl[2][GBN][GBK];  // 2 x  8 KB

    const int tid = threadIdx.x;
    const int w  = tid >> 6, l = tid & 63;
    const int wm = w;                       // wave row (0/1)

    // XCD-chunked swizzle: 800 blocks -> 8 chunks of 100; within a chunk,
    // consecutive blocks iterate N-tiles for the same A-panel.
    const int bid = blockIdx.x;
    const int swz = (bid & 7) * 100 + (bid >> 3);
    const int i0 = (swz >> 4) * GBM;        // M-tile 0..49
    const int j0 = (swz & 15) * GBN;        // N-tile 0..15

    // staging: thread t writes LDS row q*16 + (t>>3), 16B slot (t&7) of a
    // 128B row (linear dest); source column pre-swizzled (XOR row&7).
    const int srow = tid >> 3;                       // 0..15
    const int scol = 8 * ((l & 7) ^ (l >> 3));       // pre-swizzled src col

    // fragment addressing (16x16x32: row = l&15, k-off = (l>>4)*8)
    const int fr = l & 15;
    const int kg = (l >> 4) * 8;
    const int rsw = 8 * (fr & 7);                    // read-side XOR

    f32x4 acc[4][4] = {};

    auto stage = [&](int buf, int t) {
        const size_t k0 = (size_t)t * GBK;
        #pragma unroll
        for (int q = 0; q < 8; ++q) {                // A: 128 rows
            const int row = q * 16 + srow;
            __builtin_amdgcn_global_load_lds(
                (const __attribute__((address_space(1))) void*)
                    (A + (size_t)(i0 + row) * Fc + k0 + scol),
                (__attribute__((address_space(3))) void*)
                    ((char*)&Al[buf][0][0] + q * 2048 + w * 1024),
                16, 0, 0);
        }
        #pragma unroll
        for (int q = 0; q < 4; ++q) {                // B: 64 rows
            const int row = q * 16 + srow;
            __builtin_amdgcn_global_load_lds(
                (const __attribute__((address_space(1))) void*)
                    (B + (size_t)(j0 + row) * Fc + k0 + scol),
                (__attribute__((address_space(3))) void*)
                    ((char*)&Bl[buf][0][0] + q * 2048 + w * 1024),
                16, 0, 0);
        }
    };

    auto compute = [&](int buf) {
        #pragma unroll
        for (int kk = 0; kk < 2; ++kk) {
            bf16x8 af[4], bfr[4];
            #pragma unroll
            for (int mi = 0; mi < 4; ++mi)
                af[mi] = *(const bf16x8*)
                    &Al[buf][wm*64 + mi*16 + fr][(kk*32 + kg) ^ rsw];
            #pragma unroll
            for (int ni = 0; ni < 4; ++ni)
                bfr[ni] = *(const bf16x8*)
                    &Bl[buf][ni*16 + fr][(kk*32 + kg) ^ rsw];
            #pragma unroll
            for (int mi = 0; mi < 4; ++mi)
                #pragma unroll
                for (int ni = 0; ni < 4; ++ni)
                    acc[mi][ni] = __builtin_amdgcn_mfma_f32_16x16x32_bf16(
                        af[mi], bfr[ni], acc[mi][ni], 0, 0, 0);
        }
    };

    stage(0, 0);
    SYNC();
    int t = 0;
    for (; t + 2 < NT; t += 2) {
        stage(1, t + 1);  compute(0);  SYNC();
        stage(0, t + 2);  compute(1);  SYNC();
    }
    stage(1, NT - 1);  compute(0);  SYNC();
    compute(1);

    // epilogue -> bf16 P. C/D layout: col=l&15, row=(l>>4)*4+reg [m89/m91]
    const int cn = l & 15;
    const int cr = (l >> 4) * 4;
    #pragma unroll
    for (int mi = 0; mi < 4; ++mi) {
        #pragma unroll
        for (int ni = 0; ni < 4; ++ni) {
            #pragma unroll
            for (int r = 0; r < 4; ++r) {
                const int row = i0 + wm * 64 + mi * 16 + cr + r;
                const int col = j0 + ni * 16 + cn;
                P[(size_t)row * MO + col] = f2bf(acc[mi][ni][r]);
            }
        }
    }
}

// ---------------------------------------------------------------------------
// Phase A: per-(b,n) normalized gaussian weights folded with adj.
// ---------------------------------------------------------------------------
__device__ __forceinline__ void compute_a(
    int bn, int tid,
    const float* __restrict__ coord, const float* __restrict__ adj,
    const int* __restrict__ top_ind,
    const float* __restrict__ mean_rho, const float* __restrict__ mean_theta,
    const float* __restrict__ prec_rho, const float* __restrict__ prec_theta,
    int (&lds_idx)[Kc], float (&lds_a)[Kc][NKc], float (&lds_scale)[Kc])
{
    if (tid < Kc) lds_idx[tid] = top_ind[bn * Kc + tid];
    __syncthreads();
    if (tid < Kc * NKc) {
        const int k = tid >> 3, m = tid & 7;
        const int j = lds_idx[k];
        const float rho   = coord[((size_t)bn * Nc + j) * 2 + 0];
        const float theta = coord[((size_t)bn * Nc + j) * 2 + 1];
        const float dr = rho - mean_rho[m];
        const float pr = prec_rho[m];
        const float wr = expf(-0.5f * dr * dr / (1e-14f + pr * pr));
        const float fa = fabsf(theta - mean_theta[m]);
        const float sa = fabsf(TWO_PI - fa);
        const float da = fminf(fa, sa);
        const float pt = prec_theta[m];
        const float wt = expf(-0.5f * da * da / (1e-14f + pt * pt));
        float w = wr * wt;
        if (w != w) w = 0.0f;
        lds_a[k][m] = w;
    }
    __syncthreads();
    if (tid < Kc) {
        float s = 0.f;
        #pragma unroll
        for (int m = 0; m < NKc; ++m) s += lds_a[tid][m];
        lds_scale[tid] = adj[bn * Kc + tid] / (s + 1e-14f);
    }
    __syncthreads();
    if (tid < Kc * NKc) {
        const int k = tid >> 3, m = tid & 7;
        lds_a[k][m] *= lds_scale[k];
    }
    __syncthreads();
}

// ---------------------------------------------------------------------------
// Combine (bf16 P): out[bn][mo] = sum_k a[k][mo>>7] * P[b*Nc+idx[k]][mo]
// XCD-chunked bn swizzle: each XCD works an 8-batch P window (1.6 MB, L2).
// ---------------------------------------------------------------------------
__global__ __launch_bounds__(256) void combine_bf16(
    const unsigned short* __restrict__ P,
    const float* __restrict__ coord, const float* __restrict__ adj,
    const int* __restrict__ top_ind,
    const float* __restrict__ mr, const float* __restrict__ mt,
    const float* __restrict__ pr, const float* __restrict__ pt,
    float* __restrict__ out)
{
    __shared__ int   lds_idx[Kc];
    __shared__ float lds_a[Kc][NKc];
    __shared__ float lds_scale[Kc];
    const int bid = blockIdx.x;
    const int bn = (bid & 7) * 800 + (bid >> 3);     // 6400 = 8 x 800
    const int tid = threadIdx.x;
    const int b = bn / Nc;

    compute_a(bn, tid, coord, adj, top_ind, mr, mt, pr, pt,
              lds_idx, lds_a, lds_scale);

    const int m = tid >> 5;
    float ak[Kc];
    size_t rowoff[Kc];
    #pragma unroll
    for (int k = 0; k < Kc; ++k) {
        ak[k] = lds_a[k][m];
        rowoff[k] = (size_t)(b * Nc + lds_idx[k]) * MO + tid * 4;
    }
    float4 acc = make_float4(0.f, 0.f, 0.f, 0.f);
    #pragma unroll
    for (int k = 0; k < Kc; ++k) {
        const ushort4 u = *(const ushort4*)&P[rowoff[k]];
        acc.x += ak[k] * bf2f(u.x); acc.y += ak[k] * bf2f(u.y);
        acc.z += ak[k] * bf2f(u.z); acc.w += ak[k] * bf2f(u.w);
    }
    *(float4*)&out[(size_t)bn * MO + tid * 4] = acc;
}

// ---------------------------------------------------------------------------
// Fallback fp32 path (only if ws too small for bf16 path)
// ---------------------------------------------------------------------------
#define TM 64
#define TN 64
#define FBK 16

__global__ __launch_bounds__(256) void gemm_p(
    const float* __restrict__ A,
    const float* __restrict__ Bm,
    float* __restrict__ P)
{
    __shared__ float At[FBK][TM + 4];
    __shared__ float Bt[FBK][TN + 4];
    const int tid = threadIdx.x;
    const int tx = tid & 15;
    const int ty = tid >> 4;
    const int i0 = blockIdx.x * TM;
    const int j0 = blockIdx.y * TN;
    const int lk = tid & 15;
    const int lr = tid >> 4;

    float acc[4][4] = {};

    for (int k0 = 0; k0 < Fc; k0 += FBK) {
        #pragma unroll
        for (int rr = 0; rr < 4; ++rr) {
            At[lk][lr + rr * 16] = A[(size_t)(i0 + lr + rr * 16) * Fc + k0 + lk];
            Bt[lk][lr + rr * 16] = Bm[(size_t)(j0 + lr + rr * 16) * Fc + k0 + lk];
        }
        __syncthreads();
        #pragma unroll
        for (int kk = 0; kk < FBK; ++kk) {
            float a4[4], b4[4];
            #pragma unroll
            for (int p = 0; p < 4; ++p) a4[p] = At[kk][ty * 4 + p];
            #pragma unroll
            for (int p = 0; p < 4; ++p) b4[p] = Bt[kk][tx * 4 + p];
            #pragma unroll
            for (int pi = 0; pi < 4; ++pi)
                #pragma unroll
                for (int pj = 0; pj < 4; ++pj)
                    acc[pi][pj] += a4[pi] * b4[pj];
        }
        __syncthreads();
    }

    #pragma unroll
    for (int pi = 0; pi < 4; ++pi)
        #pragma unroll
        for (int pj = 0; pj < 4; ++pj)
            P[(size_t)(i0 + ty * 4 + pi) * MO + j0 + tx * 4 + pj] = acc[pi][pj];
}

__global__ __launch_bounds__(256) void combine_f32(
    const float* __restrict__ P,
    const float* __restrict__ coord, const float* __restrict__ adj,
    const int* __restrict__ top_ind,
    const float* __restrict__ mr, const float* __restrict__ mt,
    const float* __restrict__ pr, const float* __restrict__ pt,
    float* __restrict__ out)
{
    __shared__ int   lds_idx[Kc];
    __shared__ float lds_a[Kc][NKc];
    __shared__ float lds_scale[Kc];
    const int bn = blockIdx.x;
    const int tid = threadIdx.x;
    const int b = bn / Nc;

    compute_a(bn, tid, coord, adj, top_ind, mr, mt, pr, pt,
              lds_idx, lds_a, lds_scale);

    const int m = tid >> 5;
    float ak[Kc];
    size_t rowoff[Kc];
    #pragma unroll
    for (int k = 0; k < Kc; ++k) {
        ak[k] = lds_a[k][m];
        rowoff[k] = (size_t)(b * Nc + lds_idx[k]) * MO + tid * 4;
    }
    float4 acc = make_float4(0.f, 0.f, 0.f, 0.f);
    #pragma unroll
    for (int k = 0; k < Kc; ++k) {
        const float4 p = *(const float4*)&P[rowoff[k]];
        acc.x += ak[k] * p.x; acc.y += ak[k] * p.y;
        acc.z += ak[k] * p.z; acc.w += ak[k] * p.w;
    }
    *(float4*)&out[(size_t)bn * MO + tid * 4] = acc;
}

extern "C" void kernel_launch(void* const* d_in, const int* in_sizes, int n_in,
                              void* d_out, int out_size, void* d_ws, size_t ws_size,
                              hipStream_t stream) {
    const float* v        = (const float*)d_in[0];
    const float* coord    = (const float*)d_in[2];
    const float* adj      = (const float*)d_in[3];
    const int*   top_ind  = (const int*)d_in[4];
    const float* mr       = (const float*)d_in[5];
    const float* mt       = (const float*)d_in[6];
    const float* pr       = (const float*)d_in[7];
    const float* pt       = (const float*)d_in[8];
    const float* W        = (const float*)d_in[9];
    float* out = (float*)d_out;

    const size_t vbBytes = (size_t)BN * Fc * sizeof(unsigned short);   // 26,214,400
    const size_t WbBytes = (size_t)MO * Fc * sizeof(unsigned short);   //  4,194,304
    const size_t PbBytes = (size_t)BN * MO * sizeof(unsigned short);   // 13,107,200
    const size_t needBF  = vbBytes + WbBytes + PbBytes;                // ~43.5 MB
    const size_t PBytes  = (size_t)BN * MO * sizeof(float);            // 26,214,400

    if (ws_size >= needBF) {
        char* ws = (char*)d_ws;
        unsigned short* vb = (unsigned short*)ws;                 // Wb follows vb
        unsigned short* Pb = (unsigned short*)(ws + vbBytes + WbBytes);

        const int n8v   = BN * Fc / 8;                 // 1,638,400
        const int n8tot = n8v + MO * Fc / 8;           // 1,900,544 = 7424*256
        cvt_both<<<7424, 256, 0, stream>>>(v, W, vb, n8v, n8tot);

        gemm_bf16_db<<<800, 128, 0, stream>>>(vb, vb + (size_t)BN * Fc, Pb);

        combine_bf16<<<BN, 256, 0, stream>>>(Pb, coord, adj, top_ind,
                                             mr, mt, pr, pt, out);
    } else if (ws_size >= PBytes) {
        float* P = (float*)d_ws;
        gemm_p<<<dim3(BN / TM, MO / TN), 256, 0, stream>>>(v, W, P);
        combine_f32<<<BN, 256, 0, stream>>>(P, coord, adj, top_ind,
                                            mr, mt, pr, pt, out);
    }
}

// Round 6
// 65.753 us; speedup vs baseline: 1.8425x; 1.8425x over previous
//
#include <hip/hip_runtime.h>
#include <math.h>

#define Bc 64
#define Nc 100
#define Fc 2048
#define Kc 16
#define NKc 8
#define BN (Bc*Nc)      // 6400
#define MO 1024
#define TWO_PI 6.283185307179586f

typedef __attribute__((ext_vector_type(8))) short bf16x8;
typedef __attribute__((ext_vector_type(4))) float f32x4;

__device__ __forceinline__ unsigned short f2bf(float x) {
    union { float f; unsigned u; } c; c.f = x;
    unsigned r = c.u + 0x7FFFu + ((c.u >> 16) & 1u);
    return (unsigned short)(r >> 16);
}
__device__ __forceinline__ float bf2f(unsigned short x) {
    return __uint_as_float((unsigned)x << 16);
}

// ---------------------------------------------------------------------------
// fused fp32 -> bf16 (RNE) for v and W (dst = [vb | Wb] contiguous)
// ---------------------------------------------------------------------------
__global__ __launch_bounds__(256) void cvt_both(
    const float* __restrict__ v, const float* __restrict__ W,
    unsigned short* __restrict__ dst, int n8v, int n8tot)
{
    for (int i = blockIdx.x * blockDim.x + threadIdx.x; i < n8tot;
         i += gridDim.x * blockDim.x) {
        const float* src = (i < n8v) ? (v + (size_t)i * 8)
                                     : (W + (size_t)(i - n8v) * 8);
        const float4 x0 = ((const float4*)src)[0];
        const float4 x1 = ((const float4*)src)[1];
        bf16x8 o;
        o[0]=(short)f2bf(x0.x); o[1]=(short)f2bf(x0.y);
        o[2]=(short)f2bf(x0.z); o[3]=(short)f2bf(x0.w);
        o[4]=(short)f2bf(x1.x); o[5]=(short)f2bf(x1.y);
        o[6]=(short)f2bf(x1.z); o[7]=(short)f2bf(x1.w);
        *(bf16x8*)(dst + (size_t)i * 8) = o;
    }
}

// ---------------------------------------------------------------------------
// weights_k: aw[bn][m][k] = adj[bn,k] * w(bn,k,m) / (sum_m w + 1e-14)
// one 128-thread block per bn (16 k x 8 m).
// ---------------------------------------------------------------------------
__global__ __launch_bounds__(128) void weights_k(
    const float* __restrict__ coord, const float* __restrict__ adj,
    const int* __restrict__ top_ind,
    const float* __restrict__ mean_rho, const float* __restrict__ mean_theta,
    const float* __restrict__ prec_rho, const float* __restrict__ prec_theta,
    float* __restrict__ aw)
{
    __shared__ int   idx[Kc];
    __shared__ float wv[Kc][NKc];
    __shared__ float sc[Kc];
    const int bn = blockIdx.x;
    const int tid = threadIdx.x;
    if (tid < Kc) idx[tid] = top_ind[bn * Kc + tid];
    __syncthreads();
    const int k = tid >> 3, m = tid & 7;
    const int j = idx[k];
    const float rho   = coord[((size_t)bn * Nc + j) * 2 + 0];
    const float theta = coord[((size_t)bn * Nc + j) * 2 + 1];
    const float dr = rho - mean_rho[m];
    const float pr = prec_rho[m];
    const float wr = expf(-0.5f * dr * dr / (1e-14f + pr * pr));
    const float fa = fabsf(theta - mean_theta[m]);
    const float sa = fabsf(TWO_PI - fa);
    const float da = fminf(fa, sa);
    const float pt = prec_theta[m];
    const float wt = expf(-0.5f * da * da / (1e-14f + pt * pt));
    float w = wr * wt;
    if (w != w) w = 0.0f;
    wv[k][m] = w;
    __syncthreads();
    if (tid < Kc) {
        float s = 0.f;
        #pragma unroll
        for (int mm = 0; mm < NKc; ++mm) s += wv[tid][mm];
        sc[tid] = adj[bn * Kc + tid] / (s + 1e-14f);
    }
    __syncthreads();
    aw[(size_t)bn * 128 + m * 16 + k] = wv[k][m] * sc[k];
}

// ---------------------------------------------------------------------------
// gemm_fused: block (b, jt) computes P_tile[112][128] = vb[b*100+r] . Wb[jt*128+c]
// (K = 2048, BK = 64, dbuf + XOR swizzle + global_load_lds, r4-proven core),
// then applies the neighbor gather-reduce in-block:
//   out[b, n, jt*128 + c] = sum_k aw[bn][jt][k] * P_tile[idx[bn][k]][c]
// P never leaves LDS. 512 blocks = exactly 2/CU. jt = bid&7 -> per-XCD B panel.
//
// smem map (61,440 B total, manual aliasing):
//   K-loop:  Al[2][112][64] bf16 @ 0      (28,672 B)
//            Bl[2][128][64] bf16 @ 28,672 (32,768 B)
//   epilogue: P_lds[112][132] bf16 @ 0    (29,568 B)  row stride 264 B
//             idx_s int[1600]    @ 30,720 ( 6,400 B)
//             aw_s  f32[1600]    @ 37,120 ( 6,400 B)
// ---------------------------------------------------------------------------
#define GBM 112
#define GBN 128
#define GBK 64
#define NT (Fc/GBK)     // 32
#define A_OFF   0
#define A_BUF   14336
#define B_OFF   28672
#define B_BUF   16384
#define IDX_OFF 30720
#define AW_OFF  37120

#define SYNC() do { asm volatile("s_waitcnt vmcnt(0)" ::: "memory"); \
                    __builtin_amdgcn_s_barrier(); \
                    __builtin_amdgcn_sched_barrier(0); } while (0)

template<int MI>
__device__ __forceinline__ void compute_tile(
    f32x4 (&acc)[4][4], const unsigned char* smem,
    int buf, int wm, int wn, int fr, int kg, int rsw)
{
    #pragma unroll
    for (int kk = 0; kk < 2; ++kk) {
        bf16x8 af[MI], bfr[4];
        #pragma unroll
        for (int mi = 0; mi < MI; ++mi)
            af[mi] = *(const bf16x8*)(smem + A_OFF + buf * A_BUF
                        + (wm * 64 + mi * 16 + fr) * 128
                        + ((kk * 32 + kg) ^ rsw) * 2);
        #pragma unroll
        for (int ni = 0; ni < 4; ++ni)
            bfr[ni] = *(const bf16x8*)(smem + B_OFF + buf * B_BUF
                        + (wn * 64 + ni * 16 + fr) * 128
                        + ((kk * 32 + kg) ^ rsw) * 2);
        #pragma unroll
        for (int mi = 0; mi < MI; ++mi)
            #pragma unroll
            for (int ni = 0; ni < 4; ++ni)
                acc[mi][ni] = __builtin_amdgcn_mfma_f32_16x16x32_bf16(
                    af[mi], bfr[ni], acc[mi][ni], 0, 0, 0);
    }
}

__global__ __launch_bounds__(256) void gemm_fused(
    const unsigned short* __restrict__ A,   // vb [6400][2048]
    const unsigned short* __restrict__ B,   // Wb [1024][2048]
    const float* __restrict__ aw,           // [6400][8][16]
    const int* __restrict__ top_ind,        // [6400][16]
    float* __restrict__ out)                // [6400][1024]
{
    __shared__ __align__(16) unsigned char smem[61440];

    const int tid = threadIdx.x;
    const int w  = tid >> 6, l = tid & 63;
    const int wm = w & 1,  wn = w >> 1;
    const int bid = blockIdx.x;
    const int b  = bid >> 3;        // batch 0..63
    const int jt = bid & 7;         // kernel index / col tile; == XCD id
    const int i0 = b * Nc;          // row base (whole batch inside tile)
    const int j0 = jt * GBN;

    const int srow = tid >> 3;                       // 0..31
    const int scol = 8 * ((l & 7) ^ (l >> 3));       // pre-swizzled src col

    const int fr = l & 15;
    const int kg = (l >> 4) * 8;
    const int rsw = 8 * (fr & 7);

    f32x4 acc[4][4] = {};

    auto stage = [&](int buf, int t) {
        const size_t k0 = (size_t)t * GBK;
        #pragma unroll
        for (int q = 0; q < 4; ++q) {                // B: 128 rows
            const int row = q * 32 + srow;
            __builtin_amdgcn_global_load_lds(
                (const __attribute__((address_space(1))) void*)
                    (B + (size_t)(j0 + row) * Fc + k0 + scol),
                (__attribute__((address_space(3))) void*)
                    (smem + B_OFF + buf * B_BUF + q * 4096 + w * 1024),
                16, 0, 0);
        }
        #pragma unroll
        for (int q = 0; q < 3; ++q) {                // A rows 0..95 (never OOB)
            const int row = i0 + q * 32 + srow;
            __builtin_amdgcn_global_load_lds(
                (const __attribute__((address_space(1))) void*)
                    (A + (size_t)row * Fc + k0 + scol),
                (__attribute__((address_space(3))) void*)
                    (smem + A_OFF + buf * A_BUF + q * 4096 + w * 1024),
                16, 0, 0);
        }
        if (tid < 128) {                             // A rows 96..111 (clamped)
            int row = i0 + 96 + srow;
            if (row > BN - 1) row = BN - 1;
            __builtin_amdgcn_global_load_lds(
                (const __attribute__((address_space(1))) void*)
                    (A + (size_t)row * Fc + k0 + scol),
                (__attribute__((address_space(3))) void*)
                    (smem + A_OFF + buf * A_BUF + 3 * 4096 + w * 1024),
                16, 0, 0);
        }
    };

    #define COMPUTE(buf) do { \
        if (wm == 0) compute_tile<4>(acc, smem, (buf), wm, wn, fr, kg, rsw); \
        else         compute_tile<3>(acc, smem, (buf), wm, wn, fr, kg, rsw); \
    } while (0)

    stage(0, 0);
    SYNC();
    int t = 0;
    for (; t + 2 < NT; t += 2) {
        stage(1, t + 1);  COMPUTE(0);  SYNC();
        stage(0, t + 2);  COMPUTE(1);  SYNC();
    }
    stage(1, NT - 1);  COMPUTE(0);  SYNC();
    COMPUTE(1);

    // ---- epilogue: P tile -> LDS (bf16, padded stride 132) ----
    __syncthreads();
    const int cn = l & 15;
    const int cr = (l >> 4) * 4;
    const int MIw = 4 - wm;   // wave0: rows 0..63 (4 frags), wave1: 64..111 (3)
    #pragma unroll
    for (int mi = 0; mi < 4; ++mi) {
        if (mi < MIw) {
            #pragma unroll
            for (int ni = 0; ni < 4; ++ni) {
                #pragma unroll
                for (int r = 0; r < 4; ++r) {
                    const int row = wm * 64 + mi * 16 + cr + r;
                    const int col = wn * 64 + ni * 16 + cn;
                    *(unsigned short*)(smem + row * 264 + col * 2) =
                        f2bf(acc[mi][ni][r]);
                }
            }
        }
    }
    // cooperative load of idx + aw slices for this (b, jt)
    for (int i = tid; i < Nc * Kc; i += 256) {
        ((int*)(smem + IDX_OFF))[i] = top_ind[(size_t)b * Nc * Kc + i];
        ((float*)(smem + AW_OFF))[i] =
            aw[(size_t)(b * Nc + (i >> 4)) * 128 + jt * 16 + (i & 15)];
    }
    __syncthreads();

    // ---- combine: out[b,n,j0+c] = sum_k aw_k * P_lds[idx_k][c] ----
    const int cq = tid & 31;            // col quad (4 cols)
    for (int n = tid >> 5; n < Nc; n += 8) {
        float4 o = make_float4(0.f, 0.f, 0.f, 0.f);
        #pragma unroll
        for (int k = 0; k < Kc; ++k) {
            const int   r = ((const int*)(smem + IDX_OFF))[n * Kc + k];
            const float a = ((const float*)(smem + AW_OFF))[n * Kc + k];
            const ushort4 u = *(const ushort4*)(smem + r * 264 + cq * 8);
            o.x += a * bf2f(u.x); o.y += a * bf2f(u.y);
            o.z += a * bf2f(u.z); o.w += a * bf2f(u.w);
        }
        *(float4*)&out[(size_t)(b * Nc + n) * MO + j0 + cq * 4] = o;
    }
}

// ---------------------------------------------------------------------------
// Fallback fp32 path (only if ws too small for bf16 path)
// ---------------------------------------------------------------------------
#define TM 64
#define TN 64
#define FBK 16

__device__ __forceinline__ void compute_a(
    int bn, int tid,
    const float* __restrict__ coord, const float* __restrict__ adj,
    const int* __restrict__ top_ind,
    const float* __restrict__ mean_rho, const float* __restrict__ mean_theta,
    const float* __restrict__ prec_rho, const float* __restrict__ prec_theta,
    int (&lds_idx)[Kc], float (&lds_a)[Kc][NKc], float (&lds_scale)[Kc])
{
    if (tid < Kc) lds_idx[tid] = top_ind[bn * Kc + tid];
    __syncthreads();
    if (tid < Kc * NKc) {
        const int k = tid >> 3, m = tid & 7;
        const int j = lds_idx[k];
        const float rho   = coord[((size_t)bn * Nc + j) * 2 + 0];
        const float theta = coord[((size_t)bn * Nc + j) * 2 + 1];
        const float dr = rho - mean_rho[m];
        const float pr = prec_rho[m];
        const float wr = expf(-0.5f * dr * dr / (1e-14f + pr * pr));
        const float fa = fabsf(theta - mean_theta[m]);
        const float sa = fabsf(TWO_PI - fa);
        const float da = fminf(fa, sa);
        const float pt = prec_theta[m];
        const float wt = expf(-0.5f * da * da / (1e-14f + pt * pt));
        float w = wr * wt;
        if (w != w) w = 0.0f;
        lds_a[k][m] = w;
    }
    __syncthreads();
    if (tid < Kc) {
        float s = 0.f;
        #pragma unroll
        for (int m = 0; m < NKc; ++m) s += lds_a[tid][m];
        lds_scale[tid] = adj[bn * Kc + tid] / (s + 1e-14f);
    }
    __syncthreads();
    if (tid < Kc * NKc) {
        const int k = tid >> 3, m = tid & 7;
        lds_a[k][m] *= lds_scale[k];
    }
    __syncthreads();
}

__global__ __launch_bounds__(256) void gemm_p(
    const float* __restrict__ A,
    const float* __restrict__ Bm,
    float* __restrict__ P)
{
    __shared__ float At[FBK][TM + 4];
    __shared__ float Bt[FBK][TN + 4];
    const int tid = threadIdx.x;
    const int tx = tid & 15;
    const int ty = tid >> 4;
    const int i0 = blockIdx.x * TM;
    const int j0 = blockIdx.y * TN;
    const int lk = tid & 15;
    const int lr = tid >> 4;

    float acc[4][4] = {};

    for (int k0 = 0; k0 < Fc; k0 += FBK) {
        #pragma unroll
        for (int rr = 0; rr < 4; ++rr) {
            At[lk][lr + rr * 16] = A[(size_t)(i0 + lr + rr * 16) * Fc + k0 + lk];
            Bt[lk][lr + rr * 16] = Bm[(size_t)(j0 + lr + rr * 16) * Fc + k0 + lk];
        }
        __syncthreads();
        #pragma unroll
        for (int kk = 0; kk < FBK; ++kk) {
            float a4[4], b4[4];
            #pragma unroll
            for (int p = 0; p < 4; ++p) a4[p] = At[kk][ty * 4 + p];
            #pragma unroll
            for (int p = 0; p < 4; ++p) b4[p] = Bt[kk][tx * 4 + p];
            #pragma unroll
            for (int pi = 0; pi < 4; ++pi)
                #pragma unroll
                for (int pj = 0; pj < 4; ++pj)
                    acc[pi][pj] += a4[pi] * b4[pj];
        }
        __syncthreads();
    }

    #pragma unroll
    for (int pi = 0; pi < 4; ++pi)
        #pragma unroll
        for (int pj = 0; pj < 4; ++pj)
            P[(size_t)(i0 + ty * 4 + pi) * MO + j0 + tx * 4 + pj] = acc[pi][pj];
}

__global__ __launch_bounds__(256) void combine_f32(
    const float* __restrict__ P,
    const float* __restrict__ coord, const float* __restrict__ adj,
    const int* __restrict__ top_ind,
    const float* __restrict__ mr, const float* __restrict__ mt,
    const float* __restrict__ pr, const float* __restrict__ pt,
    float* __restrict__ out)
{
    __shared__ int   lds_idx[Kc];
    __shared__ float lds_a[Kc][NKc];
    __shared__ float lds_scale[Kc];
    const int bn = blockIdx.x;
    const int tid = threadIdx.x;
    const int b = bn / Nc;

    compute_a(bn, tid, coord, adj, top_ind, mr, mt, pr, pt,
              lds_idx, lds_a, lds_scale);

    const int m = tid >> 5;
    float ak[Kc];
    size_t rowoff[Kc];
    #pragma unroll
    for (int k = 0; k < Kc; ++k) {
        ak[k] = lds_a[k][m];
        rowoff[k] = (size_t)(b * Nc + lds_idx[k]) * MO + tid * 4;
    }
    float4 acc = make_float4(0.f, 0.f, 0.f, 0.f);
    #pragma unroll
    for (int k = 0; k < Kc; ++k) {
        const float4 p = *(const float4*)&P[rowoff[k]];
        acc.x += ak[k] * p.x; acc.y += ak[k] * p.y;
        acc.z += ak[k] * p.z; acc.w += ak[k] * p.w;
    }
    *(float4*)&out[(size_t)bn * MO + tid * 4] = acc;
}

extern "C" void kernel_launch(void* const* d_in, const int* in_sizes, int n_in,
                              void* d_out, int out_size, void* d_ws, size_t ws_size,
                              hipStream_t stream) {
    const float* v        = (const float*)d_in[0];
    const float* coord    = (const float*)d_in[2];
    const float* adj      = (const float*)d_in[3];
    const int*   top_ind  = (const int*)d_in[4];
    const float* mr       = (const float*)d_in[5];
    const float* mt       = (const float*)d_in[6];
    const float* pr       = (const float*)d_in[7];
    const float* pt       = (const float*)d_in[8];
    const float* W        = (const float*)d_in[9];
    float* out = (float*)d_out;

    const size_t vbBytes = (size_t)BN * Fc * sizeof(unsigned short);   // 26,214,400
    const size_t WbBytes = (size_t)MO * Fc * sizeof(unsigned short);   //  4,194,304
    const size_t awBytes = (size_t)BN * 128 * sizeof(float);           //  3,276,800
    const size_t needBF  = vbBytes + WbBytes + awBytes;                // ~33.7 MB
    const size_t PBytes  = (size_t)BN * MO * sizeof(float);            // 26,214,400

    if (ws_size >= needBF) {
        char* ws = (char*)d_ws;
        unsigned short* vb = (unsigned short*)ws;                 // Wb follows vb
        unsigned short* Wb = vb + (size_t)BN * Fc;
        float* aw          = (float*)(ws + vbBytes + WbBytes);

        const int n8v   = BN * Fc / 8;                 // 1,638,400
        const int n8tot = n8v + MO * Fc / 8;           // 1,900,544 = 7424*256
        cvt_both<<<7424, 256, 0, stream>>>(v, W, vb, n8v, n8tot);

        weights_k<<<BN, 128, 0, stream>>>(coord, adj, top_ind,
                                          mr, mt, pr, pt, aw);

        gemm_fused<<<512, 256, 0, stream>>>(vb, Wb, aw, top_ind, out);
    } else if (ws_size >= PBytes) {
        float* P = (float*)d_ws;
        gemm_p<<<dim3(BN / TM, MO / TN), 256, 0, stream>>>(v, W, P);
        combine_f32<<<BN, 256, 0, stream>>>(P, coord, adj, top_ind,
                                            mr, mt, pr, pt, out);
    }
}

// Round 7
// 60.907 us; speedup vs baseline: 1.9891x; 1.0796x over previous
//
#include <hip/hip_runtime.h>
#include <math.h>

#define Bc 64
#define Nc 100
#define Fc 2048
#define Kc 16
#define NKc 8
#define BN (Bc*Nc)      // 6400
#define MO 1024
#define TWO_PI 6.283185307179586f

typedef __attribute__((ext_vector_type(8))) short bf16x8;
typedef __attribute__((ext_vector_type(4))) float f32x4;

__device__ __forceinline__ unsigned short f2bf(float x) {
    union { float f; unsigned u; } c; c.f = x;
    unsigned r = c.u + 0x7FFFu + ((c.u >> 16) & 1u);
    return (unsigned short)(r >> 16);
}
__device__ __forceinline__ float bf2f(unsigned short x) {
    return __uint_as_float((unsigned)x << 16);
}

// ---------------------------------------------------------------------------
// prep: blocks [0, nCvt) do fp32->bf16 for [v|W]; blocks [nCvt, ...) compute
// aw[bn][m][k] = adj * w / (sum_m w + 1e-14), 2 bn per 256-thread block.
// ---------------------------------------------------------------------------
__global__ __launch_bounds__(256) void prep(
    const float* __restrict__ v, const float* __restrict__ W,
    unsigned short* __restrict__ dst, int n8v, int nCvt,
    const float* __restrict__ coord, const float* __restrict__ adj,
    const int* __restrict__ top_ind,
    const float* __restrict__ mean_rho, const float* __restrict__ mean_theta,
    const float* __restrict__ prec_rho, const float* __restrict__ prec_theta,
    float* __restrict__ aw)
{
    const int bid = blockIdx.x;
    const int tid = threadIdx.x;
    if (bid < nCvt) {
        const int i = bid * 256 + tid;       // grid sized exactly: no bounds check
        const float* src = (i < n8v) ? (v + (size_t)i * 8)
                                     : (W + (size_t)(i - n8v) * 8);
        const float4 x0 = ((const float4*)src)[0];
        const float4 x1 = ((const float4*)src)[1];
        bf16x8 o;
        o[0]=(short)f2bf(x0.x); o[1]=(short)f2bf(x0.y);
        o[2]=(short)f2bf(x0.z); o[3]=(short)f2bf(x0.w);
        o[4]=(short)f2bf(x1.x); o[5]=(short)f2bf(x1.y);
        o[6]=(short)f2bf(x1.z); o[7]=(short)f2bf(x1.w);
        *(bf16x8*)(dst + (size_t)i * 8) = o;
        return;
    }
    // ---- weights half: 2 bn per block ----
    __shared__ int   idx[2][Kc];
    __shared__ float wv[2][Kc][NKc];
    __shared__ float sc[2][Kc];
    const int h  = tid >> 7;                 // 0/1
    const int t7 = tid & 127;
    const int bn = (bid - nCvt) * 2 + h;
    if (t7 < Kc) idx[h][t7] = top_ind[bn * Kc + t7];
    __syncthreads();
    const int k = t7 >> 3, m = t7 & 7;
    const int j = idx[h][k];
    const float rho   = coord[((size_t)bn * Nc + j) * 2 + 0];
    const float theta = coord[((size_t)bn * Nc + j) * 2 + 1];
    const float dr = rho - mean_rho[m];
    const float pr = prec_rho[m];
    const float wr = expf(-0.5f * dr * dr / (1e-14f + pr * pr));
    const float fa = fabsf(theta - mean_theta[m]);
    const float sa = fabsf(TWO_PI - fa);
    const float da = fminf(fa, sa);
    const float pt = prec_theta[m];
    const float wt = expf(-0.5f * da * da / (1e-14f + pt * pt));
    float w = wr * wt;
    if (w != w) w = 0.0f;
    wv[h][k][m] = w;
    __syncthreads();
    if (t7 < Kc) {
        float s = 0.f;
        #pragma unroll
        for (int mm = 0; mm < NKc; ++mm) s += wv[h][t7][mm];
        sc[h][t7] = adj[bn * Kc + t7] / (s + 1e-14f);
    }
    __syncthreads();
    aw[(size_t)bn * 128 + m * 16 + k] = wv[h][k][m] * sc[h][k];
}

// ---------------------------------------------------------------------------
// gemm_fused: block (b, jt) computes P_tile[112][128] = vb[b*100+r] . Wb[jt*128+c]
// (K=2048, BK=64, dbuf + XOR swizzle + global_load_lds, r4/r6-proven core),
// then the in-LDS neighbor gather-reduce. P never leaves LDS.
//
// XCD-LOCAL MAPPING (r7): all 8 jt-blocks of one batch land on the same XCD
//   xcd = bid&7; slot = bid>>3; b = xcd*8 + (slot>>3); jt = slot&7
// (same-XCD under both round-robin and chunked bid->XCD policies), so the
// A-panel (458 KB) is fetched from HBM once and L2-served to the other 7.
//
// smem map (61,440 B, manual aliasing):
//   K-loop:  Al[2][112][64] bf16 @ 0      (28,672 B)
//            Bl[2][128][64] bf16 @ 28,672 (32,768 B)
//   epilogue: P_lds[112][132] bf16 @ 0    (29,568 B)  row stride 264 B
//             idx_s int[1600]    @ 30,720; aw_s f32[1600] @ 37,120
// ---------------------------------------------------------------------------
#define GBM 112
#define GBN 128
#define GBK 64
#define NT (Fc/GBK)     // 32
#define A_OFF   0
#define A_BUF   14336
#define B_OFF   28672
#define B_BUF   16384
#define IDX_OFF 30720
#define AW_OFF  37120

#define SYNC() do { asm volatile("s_waitcnt vmcnt(0)" ::: "memory"); \
                    __builtin_amdgcn_s_barrier(); \
                    __builtin_amdgcn_sched_barrier(0); } while (0)

template<int MI>
__device__ __forceinline__ void compute_tile(
    f32x4 (&acc)[4][4], const unsigned char* smem,
    int buf, int wm, int wn, int fr, int kg, int rsw)
{
    #pragma unroll
    for (int kk = 0; kk < 2; ++kk) {
        bf16x8 af[MI], bfr[4];
        #pragma unroll
        for (int mi = 0; mi < MI; ++mi)
            af[mi] = *(const bf16x8*)(smem + A_OFF + buf * A_BUF
                        + (wm * 64 + mi * 16 + fr) * 128
                        + ((kk * 32 + kg) ^ rsw) * 2);
        #pragma unroll
        for (int ni = 0; ni < 4; ++ni)
            bfr[ni] = *(const bf16x8*)(smem + B_OFF + buf * B_BUF
                        + (wn * 64 + ni * 16 + fr) * 128
                        + ((kk * 32 + kg) ^ rsw) * 2);
        #pragma unroll
        for (int mi = 0; mi < MI; ++mi)
            #pragma unroll
            for (int ni = 0; ni < 4; ++ni)
                acc[mi][ni] = __builtin_amdgcn_mfma_f32_16x16x32_bf16(
                    af[mi], bfr[ni], acc[mi][ni], 0, 0, 0);
    }
}

__global__ __launch_bounds__(256) void gemm_fused(
    const unsigned short* __restrict__ A,   // vb [6400][2048]
    const unsigned short* __restrict__ B,   // Wb [1024][2048]
    const float* __restrict__ aw,           // [6400][8][16]
    const int* __restrict__ top_ind,        // [6400][16]
    float* __restrict__ out)                // [6400][1024]
{
    __shared__ __align__(16) unsigned char smem[61440];

    const int tid = threadIdx.x;
    const int w  = tid >> 6, l = tid & 63;
    const int wm = w & 1,  wn = w >> 1;
    const int bid = blockIdx.x;
    const int xcd  = bid & 7;
    const int slot = bid >> 3;               // 0..63
    const int b  = xcd * 8 + (slot >> 3);    // batch 0..63 (XCD-local)
    const int jt = slot & 7;                 // kernel index / col tile
    const int i0 = b * Nc;
    const int j0 = jt * GBN;

    const int srow = tid >> 3;                       // 0..31
    const int scol = 8 * ((l & 7) ^ (l >> 3));       // pre-swizzled src col

    const int fr = l & 15;
    const int kg = (l >> 4) * 8;
    const int rsw = 8 * (fr & 7);

    f32x4 acc[4][4] = {};

    auto stage = [&](int buf, int t) {
        const size_t k0 = (size_t)t * GBK;
        #pragma unroll
        for (int q = 0; q < 4; ++q) {                // B: 128 rows
            const int row = q * 32 + srow;
            __builtin_amdgcn_global_load_lds(
                (const __attribute__((address_space(1))) void*)
                    (B + (size_t)(j0 + row) * Fc + k0 + scol),
                (__attribute__((address_space(3))) void*)
                    (smem + B_OFF + buf * B_BUF + q * 4096 + w * 1024),
                16, 0, 0);
        }
        #pragma unroll
        for (int q = 0; q < 3; ++q) {                // A rows 0..95
            const int row = i0 + q * 32 + srow;
            __builtin_amdgcn_global_load_lds(
                (const __attribute__((address_space(1))) void*)
                    (A + (size_t)row * Fc + k0 + scol),
                (__attribute__((address_space(3))) void*)
                    (smem + A_OFF + buf * A_BUF + q * 4096 + w * 1024),
                16, 0, 0);
        }
        if (tid < 128) {                             // A rows 96..111 (clamped)
            int row = i0 + 96 + srow;
            if (row > BN - 1) row = BN - 1;
            __builtin_amdgcn_global_load_lds(
                (const __attribute__((address_space(1))) void*)
                    (A + (size_t)row * Fc + k0 + scol),
                (__attribute__((address_space(3))) void*)
                    (smem + A_OFF + buf * A_BUF + 3 * 4096 + w * 1024),
                16, 0, 0);
        }
    };

    #define COMPUTE(buf) do { \
        if (wm == 0) compute_tile<4>(acc, smem, (buf), wm, wn, fr, kg, rsw); \
        else         compute_tile<3>(acc, smem, (buf), wm, wn, fr, kg, rsw); \
    } while (0)

    stage(0, 0);
    SYNC();
    int t = 0;
    for (; t + 2 < NT; t += 2) {
        stage(1, t + 1);  COMPUTE(0);  SYNC();
        stage(0, t + 2);  COMPUTE(1);  SYNC();
    }
    stage(1, NT - 1);  COMPUTE(0);  SYNC();
    COMPUTE(1);

    // ---- epilogue: P tile -> LDS (bf16, padded stride 132) ----
    __syncthreads();
    const int cn = l & 15;
    const int cr = (l >> 4) * 4;
    const int MIw = 4 - wm;
    #pragma unroll
    for (int mi = 0; mi < 4; ++mi) {
        if (mi < MIw) {
            #pragma unroll
            for (int ni = 0; ni < 4; ++ni) {
                #pragma unroll
                for (int r = 0; r < 4; ++r) {
                    const int row = wm * 64 + mi * 16 + cr + r;
                    const int col = wn * 64 + ni * 16 + cn;
                    *(unsigned short*)(smem + row * 264 + col * 2) =
                        f2bf(acc[mi][ni][r]);
                }
            }
        }
    }
    for (int i = tid; i < Nc * Kc; i += 256) {
        ((int*)(smem + IDX_OFF))[i] = top_ind[(size_t)b * Nc * Kc + i];
        ((float*)(smem + AW_OFF))[i] =
            aw[(size_t)(b * Nc + (i >> 4)) * 128 + jt * 16 + (i & 15)];
    }
    __syncthreads();

    // ---- combine: out[b,n,j0+c] = sum_k aw_k * P_lds[idx_k][c] ----
    const int cq = tid & 31;
    for (int n = tid >> 5; n < Nc; n += 8) {
        float4 o = make_float4(0.f, 0.f, 0.f, 0.f);
        #pragma unroll
        for (int k = 0; k < Kc; ++k) {
            const int   r = ((const int*)(smem + IDX_OFF))[n * Kc + k];
            const float a = ((const float*)(smem + AW_OFF))[n * Kc + k];
            const ushort4 u = *(const ushort4*)(smem + r * 264 + cq * 8);
            o.x += a * bf2f(u.x); o.y += a * bf2f(u.y);
            o.z += a * bf2f(u.z); o.w += a * bf2f(u.w);
        }
        *(float4*)&out[(size_t)(b * Nc + n) * MO + j0 + cq * 4] = o;
    }
}

// ---------------------------------------------------------------------------
// Fallback fp32 path (only if ws too small for bf16 path)
// ---------------------------------------------------------------------------
#define TM 64
#define TN 64
#define FBK 16

__device__ __forceinline__ void compute_a(
    int bn, int tid,
    const float* __restrict__ coord, const float* __restrict__ adj,
    const int* __restrict__ top_ind,
    const float* __restrict__ mean_rho, const float* __restrict__ mean_theta,
    const float* __restrict__ prec_rho, const float* __restrict__ prec_theta,
    int (&lds_idx)[Kc], float (&lds_a)[Kc][NKc], float (&lds_scale)[Kc])
{
    if (tid < Kc) lds_idx[tid] = top_ind[bn * Kc + tid];
    __syncthreads();
    if (tid < Kc * NKc) {
        const int k = tid >> 3, m = tid & 7;
        const int j = lds_idx[k];
        const float rho   = coord[((size_t)bn * Nc + j) * 2 + 0];
        const float theta = coord[((size_t)bn * Nc + j) * 2 + 1];
        const float dr = rho - mean_rho[m];
        const float pr = prec_rho[m];
        const float wr = expf(-0.5f * dr * dr / (1e-14f + pr * pr));
        const float fa = fabsf(theta - mean_theta[m]);
        const float sa = fabsf(TWO_PI - fa);
        const float da = fminf(fa, sa);
        const float pt = prec_theta[m];
        const float wt = expf(-0.5f * da * da / (1e-14f + pt * pt));
        float w = wr * wt;
        if (w != w) w = 0.0f;
        lds_a[k][m] = w;
    }
    __syncthreads();
    if (tid < Kc) {
        float s = 0.f;
        #pragma unroll
        for (int m = 0; m < NKc; ++m) s += lds_a[tid][m];
        lds_scale[tid] = adj[bn * Kc + tid] / (s + 1e-14f);
    }
    __syncthreads();
    if (tid < Kc * NKc) {
        const int k = tid >> 3, m = tid & 7;
        lds_a[k][m] *= lds_scale[k];
    }
    __syncthreads();
}

__global__ __launch_bounds__(256) void gemm_p(
    const float* __restrict__ A,
    const float* __restrict__ Bm,
    float* __restrict__ P)
{
    __shared__ float At[FBK][TM + 4];
    __shared__ float Bt[FBK][TN + 4];
    const int tid = threadIdx.x;
    const int tx = tid & 15;
    const int ty = tid >> 4;
    const int i0 = blockIdx.x * TM;
    const int j0 = blockIdx.y * TN;
    const int lk = tid & 15;
    const int lr = tid >> 4;

    float acc[4][4] = {};

    for (int k0 = 0; k0 < Fc; k0 += FBK) {
        #pragma unroll
        for (int rr = 0; rr < 4; ++rr) {
            At[lk][lr + rr * 16] = A[(size_t)(i0 + lr + rr * 16) * Fc + k0 + lk];
            Bt[lk][lr + rr * 16] = Bm[(size_t)(j0 + lr + rr * 16) * Fc + k0 + lk];
        }
        __syncthreads();
        #pragma unroll
        for (int kk = 0; kk < FBK; ++kk) {
            float a4[4], b4[4];
            #pragma unroll
            for (int p = 0; p < 4; ++p) a4[p] = At[kk][ty * 4 + p];
            #pragma unroll
            for (int p = 0; p < 4; ++p) b4[p] = Bt[kk][tx * 4 + p];
            #pragma unroll
            for (int pi = 0; pi < 4; ++pi)
                #pragma unroll
                for (int pj = 0; pj < 4; ++pj)
                    acc[pi][pj] += a4[pi] * b4[pj];
        }
        __syncthreads();
    }

    #pragma unroll
    for (int pi = 0; pi < 4; ++pi)
        #pragma unroll
        for (int pj = 0; pj < 4; ++pj)
            P[(size_t)(i0 + ty * 4 + pi) * MO + j0 + tx * 4 + pj] = acc[pi][pj];
}

__global__ __launch_bounds__(256) void combine_f32(
    const float* __restrict__ P,
    const float* __restrict__ coord, const float* __restrict__ adj,
    const int* __restrict__ top_ind,
    const float* __restrict__ mr, const float* __restrict__ mt,
    const float* __restrict__ pr, const float* __restrict__ pt,
    float* __restrict__ out)
{
    __shared__ int   lds_idx[Kc];
    __shared__ float lds_a[Kc][NKc];
    __shared__ float lds_scale[Kc];
    const int bn = blockIdx.x;
    const int tid = threadIdx.x;
    const int b = bn / Nc;

    compute_a(bn, tid, coord, adj, top_ind, mr, mt, pr, pt,
              lds_idx, lds_a, lds_scale);

    const int m = tid >> 5;
    float ak[Kc];
    size_t rowoff[Kc];
    #pragma unroll
    for (int k = 0; k < Kc; ++k) {
        ak[k] = lds_a[k][m];
        rowoff[k] = (size_t)(b * Nc + lds_idx[k]) * MO + tid * 4;
    }
    float4 acc = make_float4(0.f, 0.f, 0.f, 0.f);
    #pragma unroll
    for (int k = 0; k < Kc; ++k) {
        const float4 p = *(const float4*)&P[rowoff[k]];
        acc.x += ak[k] * p.x; acc.y += ak[k] * p.y;
        acc.z += ak[k] * p.z; acc.w += ak[k] * p.w;
    }
    *(float4*)&out[(size_t)bn * MO + tid * 4] = acc;
}

extern "C" void kernel_launch(void* const* d_in, const int* in_sizes, int n_in,
                              void* d_out, int out_size, void* d_ws, size_t ws_size,
                              hipStream_t stream) {
    const float* v        = (const float*)d_in[0];
    const float* coord    = (const float*)d_in[2];
    const float* adj      = (const float*)d_in[3];
    const int*   top_ind  = (const int*)d_in[4];
    const float* mr       = (const float*)d_in[5];
    const float* mt       = (const float*)d_in[6];
    const float* pr       = (const float*)d_in[7];
    const float* pt       = (const float*)d_in[8];
    const float* W        = (const float*)d_in[9];
    float* out = (float*)d_out;

    const size_t vbBytes = (size_t)BN * Fc * sizeof(unsigned short);   // 26,214,400
    const size_t WbBytes = (size_t)MO * Fc * sizeof(unsigned short);   //  4,194,304
    const size_t awBytes = (size_t)BN * 128 * sizeof(float);           //  3,276,800
    const size_t needBF  = vbBytes + WbBytes + awBytes;                // ~33.7 MB
    const size_t PBytes  = (size_t)BN * MO * sizeof(float);            // 26,214,400

    if (ws_size >= needBF) {
        char* ws = (char*)d_ws;
        unsigned short* vb = (unsigned short*)ws;                 // Wb follows vb
        unsigned short* Wb = vb + (size_t)BN * Fc;
        float* aw          = (float*)(ws + vbBytes + WbBytes);

        const int n8v   = BN * Fc / 8;                 // 1,638,400
        const int nCvt  = (n8v + MO * Fc / 8) / 256;   // 7424 (exact)
        const int nWgt  = BN / 2;                      // 3200
        prep<<<nCvt + nWgt, 256, 0, stream>>>(v, W, vb, n8v, nCvt,
                                              coord, adj, top_ind,
                                              mr, mt, pr, pt, aw);

        gemm_fused<<<512, 256, 0, stream>>>(vb, Wb, aw, top_ind, out);
    } else if (ws_size >= PBytes) {
        float* P = (float*)d_ws;
        gemm_p<<<dim3(BN / TM, MO / TN), 256, 0, stream>>>(v, W, P);
        combine_f32<<<BN, 256, 0, stream>>>(P, coord, adj, top_ind,
                                            mr, mt, pr, pt, out);
    }
}